// Round 16
// baseline (185.029 us; speedup 1.0000x reference)
//
#include <hip/hip_runtime.h>
#include <math.h>

#define NB 2048
#define ND 784
#define NK 128
#define KP 3136            // 4*784: K = 4d+c, A slots {m*x^2, m*x, m, 0}
#define NSTEP 98           // KP/32 k-steps
#define KSPLIT 14          // K-chunks -> partials
#define SPK 7              // k-steps per chunk
#define MT 64              // rows per k_mm block (4 waves x 16 rows)
#define NHALF 2            // N-split: each wave does 4 nt = 64 cols
#define NFIX (NHALF * KSPLIT)   // blocks contributing to one mt = 28

typedef __attribute__((ext_vector_type(8))) short short8;
typedef __attribute__((ext_vector_type(4))) float f32x4;

// ws float offsets:
#define OFF_CNT  0                        // 32 ints (split-K fixup counters)
#define OFF_PART 32
#define N_PART   (KSPLIT * NB * NK)       // 3,670,016 floats (14.7 MB)
#define OFF_BH   (OFF_PART + N_PART)
#define N_B_F    (NSTEP * 8 * 64 * 4)     // 200,704 float slots per table
#define OFF_BL   (OFF_BH + N_B_F)

__device__ inline ushort f2bf(float f) {   // round-to-nearest-even f32->bf16
  uint u = __float_as_uint(f);
  return (ushort)((u + 0x7FFFu + ((u >> 16) & 1u)) >> 16);
}

// B-prep, COALESCED: thread g -> (n = g/392, dpair = g%392), reads
// cov/mu[n][2dp..2dp+1] as float2 (consecutive lanes = consecutive dims ->
// 512B/wave coalesced). Produces the same fragment-linear hi/lo B as before
// (bit-identical math). Also zeroes the 32 fixup counters.
__global__ __launch_bounds__(256) void k_prep(
    const float* __restrict__ mu, const float* __restrict__ cov,
    float* __restrict__ ws) {
  int g = blockIdx.x * 256 + threadIdx.x;   // 0..50175
  if (g < 32) ((int*)(ws + OFF_CNT))[g] = 0;
  int n  = g / 392;
  int dp = g - n * 392;
  int d0 = dp * 2;
  float2 cv = *(const float2*)(cov + (size_t)n * ND + d0);
  float2 mv = *(const float2*)(mu  + (size_t)n * ND + d0);
  float va[8];
  va[0] = -0.5f / cv.x;
  va[1] = mv.x / cv.x;
  va[2] = -mv.x * mv.x * 0.5f / cv.x - 0.5f * logf(cv.x);
  va[3] = 0.f;
  va[4] = -0.5f / cv.y;
  va[5] = mv.y / cv.y;
  va[6] = -mv.y * mv.y * 0.5f / cv.y - 0.5f * logf(cv.y);
  va[7] = 0.f;
  ushort hi[8], lo[8];
#pragma unroll
  for (int j = 0; j < 8; j++) {
    ushort h = f2bf(va[j]);
    hi[j] = h;
    lo[j] = f2bf(va[j] - __uint_as_float(((uint)h) << 16));
  }
  uint4 vh, vl;
  vh.x = (uint)hi[0] | ((uint)hi[1] << 16);
  vh.y = (uint)hi[2] | ((uint)hi[3] << 16);
  vh.z = (uint)hi[4] | ((uint)hi[5] << 16);
  vh.w = (uint)hi[6] | ((uint)hi[7] << 16);
  vl.x = (uint)lo[0] | ((uint)lo[1] << 16);
  vl.y = (uint)lo[2] | ((uint)lo[3] << 16);
  vl.z = (uint)lo[4] | ((uint)lo[5] << 16);
  vl.w = (uint)lo[6] | ((uint)lo[7] << 16);
  int ks = dp >> 2, lg = dp & 3, nt = n >> 4, nl = n & 15;
  int fid = ks * 8 + nt;
  int lp  = lg * 16 + nl;
  ((uint4*)(ws + OFF_BH))[fid * 64 + lp] = vh;
  ((uint4*)(ws + OFF_BL))[fid * 64 + lp] = vl;
}

// GEMM (R15 main loop, unchanged) + fused split-K fixup: the 28th block to
// finish an mt row-tile reduces partials, adds log w, NaN-fix, LSE, writes out.
__global__ __launch_bounds__(256, 4) void k_mm(
    const float* __restrict__ data, const float* __restrict__ mask,
    const float* __restrict__ wts, float* __restrict__ ws,
    float* __restrict__ out) {
  const short8* Bh = (const short8*)(ws + OFF_BH);
  const short8* Bl = (const short8*)(ws + OFF_BL);
  float* part = ws + OFF_PART;

  int bid = blockIdx.x;
  int mt  = bid / (NHALF * KSPLIT);
  int rem = bid % (NHALF * KSPLIT);
  int nh  = rem / KSPLIT;
  int kc  = rem % KSPLIT;
  int w   = threadIdx.x >> 6;
  int l   = threadIdx.x & 63;
  int r0  = mt * MT + w * 16;
  int rowA = r0 + (l & 15);
  int g2   = (l >> 4) << 1;     // dim offset within k-step: 0,2,4,6
  int n0   = nh * 4;            // first nt of this wave

  const float* dp = data + (size_t)rowA * ND + g2;
  const float* mp = mask + (size_t)rowA * ND + g2;

  // ---- pre-load all x/m for this chunk (14 independent 8B loads)
  float2 xs[SPK], ms[SPK];
#pragma unroll
  for (int s = 0; s < SPK; s++) {
    int ks = kc * SPK + s;
    xs[s] = *(const float2*)(dp + ks * 8);
    ms[s] = *(const float2*)(mp + ks * 8);
  }

  // ---- pre-convert all A fragments (off the k-loop critical path)
  short8 ah[SPK], al[SPK];
#pragma unroll
  for (int s = 0; s < SPK; s++) {
    float2 x = xs[s], m = ms[s];
    float mx0 = m.x * x.x, mq0 = mx0 * x.x;
    float mx1 = m.y * x.y, mq1 = mx1 * x.y;
    ushort h_q0 = f2bf(mq0), h_x0 = f2bf(mx0);
    ushort h_q1 = f2bf(mq1), h_x1 = f2bf(mx1);
    ushort h_m0 = (ushort)(__float_as_uint(m.x) >> 16);  // exact: m in {0,1}
    ushort h_m1 = (ushort)(__float_as_uint(m.y) >> 16);
    float r_q0 = mq0 - __uint_as_float(((uint)h_q0) << 16);
    float r_x0 = mx0 - __uint_as_float(((uint)h_x0) << 16);
    float r_q1 = mq1 - __uint_as_float(((uint)h_q1) << 16);
    float r_x1 = mx1 - __uint_as_float(((uint)h_x1) << 16);
    ah[s][0] = (short)h_q0;       ah[s][1] = (short)h_x0;
    ah[s][2] = (short)h_m0;       ah[s][3] = 0;
    ah[s][4] = (short)h_q1;       ah[s][5] = (short)h_x1;
    ah[s][6] = (short)h_m1;       ah[s][7] = 0;
    al[s][0] = (short)f2bf(r_q0); al[s][1] = (short)f2bf(r_x0);
    al[s][2] = 0;                 al[s][3] = 0;
    al[s][4] = (short)f2bf(r_q1); al[s][5] = (short)f2bf(r_x1);
    al[s][6] = 0;                 al[s][7] = 0;
  }

  f32x4 acc[4];
#pragma unroll
  for (int i = 0; i < 4; i++) acc[i] = (f32x4){0.f, 0.f, 0.f, 0.f};

#pragma unroll
  for (int s = 0; s < SPK; s++) {
    int ks = kc * SPK + s;
    const short8* bh = Bh + ((size_t)(ks * 8) + n0) * 64 + l;
    const short8* bl = Bl + ((size_t)(ks * 8) + n0) * 64 + l;
    short8 b_h0 = bh[0], b_h1 = bh[64], b_h2 = bh[128], b_h3 = bh[192];
    short8 b_l0 = bl[0], b_l1 = bl[64], b_l2 = bl[128], b_l3 = bl[192];

    acc[0] = __builtin_amdgcn_mfma_f32_16x16x32_bf16(ah[s], b_h0, acc[0], 0, 0, 0);
    acc[0] = __builtin_amdgcn_mfma_f32_16x16x32_bf16(ah[s], b_l0, acc[0], 0, 0, 0);
    acc[0] = __builtin_amdgcn_mfma_f32_16x16x32_bf16(al[s], b_h0, acc[0], 0, 0, 0);
    acc[1] = __builtin_amdgcn_mfma_f32_16x16x32_bf16(ah[s], b_h1, acc[1], 0, 0, 0);
    acc[1] = __builtin_amdgcn_mfma_f32_16x16x32_bf16(ah[s], b_l1, acc[1], 0, 0, 0);
    acc[1] = __builtin_amdgcn_mfma_f32_16x16x32_bf16(al[s], b_h1, acc[1], 0, 0, 0);
    acc[2] = __builtin_amdgcn_mfma_f32_16x16x32_bf16(ah[s], b_h2, acc[2], 0, 0, 0);
    acc[2] = __builtin_amdgcn_mfma_f32_16x16x32_bf16(ah[s], b_l2, acc[2], 0, 0, 0);
    acc[2] = __builtin_amdgcn_mfma_f32_16x16x32_bf16(al[s], b_h2, acc[2], 0, 0, 0);
    acc[3] = __builtin_amdgcn_mfma_f32_16x16x32_bf16(ah[s], b_h3, acc[3], 0, 0, 0);
    acc[3] = __builtin_amdgcn_mfma_f32_16x16x32_bf16(ah[s], b_l3, acc[3], 0, 0, 0);
    acc[3] = __builtin_amdgcn_mfma_f32_16x16x32_bf16(al[s], b_h3, acc[3], 0, 0, 0);
  }

#pragma unroll
  for (int ntl = 0; ntl < 4; ntl++)
#pragma unroll
    for (int r = 0; r < 4; r++) {
      int grow = r0 + ((l >> 4) << 2) + r;
      part[((size_t)kc * NB + grow) * NK + (n0 + ntl) * 16 + (l & 15)] = acc[ntl][r];
    }

  // ---- split-K fixup: last of the 28 blocks for this mt reduces + writes out
  __shared__ int do_fix;
  __threadfence();                 // make this block's partials device-visible
  __syncthreads();                 // (implies vmcnt drain of the stores)
  if (threadIdx.x == 0) {
    int old = atomicAdd(&((int*)(ws + OFF_CNT))[mt], 1);  // device scope
    do_fix = (old == NFIX - 1);
  }
  __syncthreads();
  if (!do_fix) return;
  __threadfence();                 // acquire: other blocks' partials visible

  // 4 threads per row: row = tid>>2, sub = tid&3 handles float4s q*4+sub.
  int row = mt * MT + (threadIdx.x >> 2);
  int sub = threadIdx.x & 3;
  const float4* p4 = (const float4*)(ws + OFF_PART);
  float4 sv[8];
#pragma unroll
  for (int q = 0; q < 8; q++) sv[q] = make_float4(0.f, 0.f, 0.f, 0.f);
  for (int sp = 0; sp < KSPLIT; sp++) {
    const float4* pr = p4 + ((size_t)sp * NB + row) * 32;
#pragma unroll
    for (int q = 0; q < 8; q++) {
      float4 v = pr[q * 4 + sub];
      sv[q].x += v.x; sv[q].y += v.y; sv[q].z += v.z; sv[q].w += v.w;
    }
  }
#pragma unroll
  for (int q = 0; q < 8; q++) {
    int k = (q * 4 + sub) * 4;
    float4 wv = *(const float4*)(wts + k);
    sv[q].x += logf(wv.x); sv[q].y += logf(wv.y);
    sv[q].z += logf(wv.z); sv[q].w += logf(wv.w);
    if (isnan(sv[q].x)) sv[q].x = 0.f;
    if (isnan(sv[q].y)) sv[q].y = 0.f;
    if (isnan(sv[q].z)) sv[q].z = 0.f;
    if (isnan(sv[q].w)) sv[q].w = 0.f;
  }
  float mx = -3.402823466e+38f;
#pragma unroll
  for (int q = 0; q < 8; q++) {
    mx = fmaxf(mx, fmaxf(fmaxf(sv[q].x, sv[q].y), fmaxf(sv[q].z, sv[q].w)));
  }
  mx = fmaxf(mx, __shfl_xor(mx, 1));
  mx = fmaxf(mx, __shfl_xor(mx, 2));
  float sum = 32e-8f;              // 32 elems x the reference's +1e-8
#pragma unroll
  for (int q = 0; q < 8; q++) {
    sum += expf(sv[q].x - mx) + expf(sv[q].y - mx)
         + expf(sv[q].z - mx) + expf(sv[q].w - mx);
  }
  sum += __shfl_xor(sum, 1);
  sum += __shfl_xor(sum, 2);
  float lse = logf(sum) + mx;
  float4* o4 = (float4*)out + (size_t)row * 32;
#pragma unroll
  for (int q = 0; q < 8; q++) {
    float4 o = make_float4(expf(sv[q].x - lse), expf(sv[q].y - lse),
                           expf(sv[q].z - lse), expf(sv[q].w - lse));
    o4[q * 4 + sub] = o;
  }
}

extern "C" void kernel_launch(void* const* d_in, const int* in_sizes, int n_in,
                              void* d_out, int out_size, void* d_ws, size_t ws_size,
                              hipStream_t stream) {
  const float* data = (const float*)d_in[0];
  const float* mask = (const float*)d_in[1];
  const float* wts  = (const float*)d_in[2];
  const float* mu   = (const float*)d_in[3];
  const float* cov  = (const float*)d_in[4];
  float* ws  = (float*)d_ws;
  float* out = (float*)d_out;

  k_prep<<<196, 256, 0, stream>>>(mu, cov, ws);
  k_mm<<<32 * NHALF * KSPLIT, 256, 0, stream>>>(data, mask, wts, ws, out);
}

// Round 17
// 30.126 us; speedup vs baseline: 6.1419x; 6.1419x over previous
//
#include <hip/hip_runtime.h>
#include <math.h>

#define NB 2048
#define ND 784
#define NK 128
#define KP 3136            // 4*784: K = 4d+c, A slots {m*x^2, m*x, m, 0}
#define NSTEP 98           // KP/32 k-steps
#define KSPLIT 14          // K-chunks -> partials
#define SPK 7              // k-steps per chunk
#define MT 64              // rows per k_mm block (4 waves x 16 rows)
#define NHALF 2            // N-split: each wave does 4 nt = 64 cols

typedef __attribute__((ext_vector_type(8))) short short8;
typedef __attribute__((ext_vector_type(4))) float f32x4;

// ws float offsets:
#define OFF_LW   0
#define OFF_PART 128
#define N_PART   (KSPLIT * NB * NK)       // 3,670,016 floats (14.7 MB)
#define OFF_BH   (OFF_PART + N_PART)
#define N_B_F    (NSTEP * 8 * 64 * 4)     // 200,704 float slots per table
#define OFF_BL   (OFF_BH + N_B_F)

__device__ inline ushort f2bf(float f) {   // round-to-nearest-even f32->bf16
  uint u = __float_as_uint(f);
  return (ushort)((u + 0x7FFFu + ((u >> 16) & 1u)) >> 16);
}

// B-prep, COALESCED: thread g -> (n = g/392, dpair = g%392), reads
// cov/mu[n][2dp..2dp+1] as float2 (consecutive lanes = consecutive dims ->
// 512B/wave coalesced). Same fragment-linear hi/lo B as the validated
// scattered version (bit-identical math; R16 passed with it). log w too.
__global__ __launch_bounds__(256) void k_prep(
    const float* __restrict__ w, const float* __restrict__ mu,
    const float* __restrict__ cov, float* __restrict__ ws) {
  int g = blockIdx.x * 256 + threadIdx.x;   // 0..50175
  if (g < NK) ws[OFF_LW + g] = logf(w[g]);
  int n  = g / 392;
  int dp = g - n * 392;
  int d0 = dp * 2;
  float2 cv = *(const float2*)(cov + (size_t)n * ND + d0);
  float2 mv = *(const float2*)(mu  + (size_t)n * ND + d0);
  float va[8];
  va[0] = -0.5f / cv.x;
  va[1] = mv.x / cv.x;
  va[2] = -mv.x * mv.x * 0.5f / cv.x - 0.5f * logf(cv.x);
  va[3] = 0.f;
  va[4] = -0.5f / cv.y;
  va[5] = mv.y / cv.y;
  va[6] = -mv.y * mv.y * 0.5f / cv.y - 0.5f * logf(cv.y);
  va[7] = 0.f;
  ushort hi[8], lo[8];
#pragma unroll
  for (int j = 0; j < 8; j++) {
    ushort h = f2bf(va[j]);
    hi[j] = h;
    lo[j] = f2bf(va[j] - __uint_as_float(((uint)h) << 16));
  }
  uint4 vh, vl;
  vh.x = (uint)hi[0] | ((uint)hi[1] << 16);
  vh.y = (uint)hi[2] | ((uint)hi[3] << 16);
  vh.z = (uint)hi[4] | ((uint)hi[5] << 16);
  vh.w = (uint)hi[6] | ((uint)hi[7] << 16);
  vl.x = (uint)lo[0] | ((uint)lo[1] << 16);
  vl.y = (uint)lo[2] | ((uint)lo[3] << 16);
  vl.z = (uint)lo[4] | ((uint)lo[5] << 16);
  vl.w = (uint)lo[6] | ((uint)lo[7] << 16);
  int ks = dp >> 2, lg = dp & 3, nt = n >> 4, nl = n & 15;
  int fid = ks * 8 + nt;
  int lp  = lg * 16 + nl;
  ((uint4*)(ws + OFF_BH))[fid * 64 + lp] = vh;
  ((uint4*)(ws + OFF_BL))[fid * 64 + lp] = vl;
}

// GEMM, PRE-CONVERTED A (R15, unchanged): k-loop is pure
// {8 batched B loads -> 12 MFMAs}. grid = 32 mt x NHALF x KSPLIT = 896,
// 4 waves, 3.5 waves/SIMD. acc layout (m89): col = lane&15,
// row = (lane>>4)*4 + reg.
__global__ __launch_bounds__(256, 4) void k_mm(
    const float* __restrict__ data, const float* __restrict__ mask,
    float* __restrict__ ws) {
  const short8* Bh = (const short8*)(ws + OFF_BH);
  const short8* Bl = (const short8*)(ws + OFF_BL);
  float* part = ws + OFF_PART;

  int bid = blockIdx.x;
  int mt  = bid / (NHALF * KSPLIT);
  int rem = bid % (NHALF * KSPLIT);
  int nh  = rem / KSPLIT;
  int kc  = rem % KSPLIT;
  int w   = threadIdx.x >> 6;
  int l   = threadIdx.x & 63;
  int r0  = mt * MT + w * 16;
  int rowA = r0 + (l & 15);
  int g2   = (l >> 4) << 1;     // dim offset within k-step: 0,2,4,6
  int n0   = nh * 4;            // first nt of this wave

  const float* dp = data + (size_t)rowA * ND + g2;
  const float* mp = mask + (size_t)rowA * ND + g2;

  float2 xs[SPK], ms[SPK];
#pragma unroll
  for (int s = 0; s < SPK; s++) {
    int ks = kc * SPK + s;
    xs[s] = *(const float2*)(dp + ks * 8);
    ms[s] = *(const float2*)(mp + ks * 8);
  }

  short8 ah[SPK], al[SPK];
#pragma unroll
  for (int s = 0; s < SPK; s++) {
    float2 x = xs[s], m = ms[s];
    float mx0 = m.x * x.x, mq0 = mx0 * x.x;
    float mx1 = m.y * x.y, mq1 = mx1 * x.y;
    ushort h_q0 = f2bf(mq0), h_x0 = f2bf(mx0);
    ushort h_q1 = f2bf(mq1), h_x1 = f2bf(mx1);
    ushort h_m0 = (ushort)(__float_as_uint(m.x) >> 16);  // exact: m in {0,1}
    ushort h_m1 = (ushort)(__float_as_uint(m.y) >> 16);
    float r_q0 = mq0 - __uint_as_float(((uint)h_q0) << 16);
    float r_x0 = mx0 - __uint_as_float(((uint)h_x0) << 16);
    float r_q1 = mq1 - __uint_as_float(((uint)h_q1) << 16);
    float r_x1 = mx1 - __uint_as_float(((uint)h_x1) << 16);
    ah[s][0] = (short)h_q0;       ah[s][1] = (short)h_x0;
    ah[s][2] = (short)h_m0;       ah[s][3] = 0;
    ah[s][4] = (short)h_q1;       ah[s][5] = (short)h_x1;
    ah[s][6] = (short)h_m1;       ah[s][7] = 0;
    al[s][0] = (short)f2bf(r_q0); al[s][1] = (short)f2bf(r_x0);
    al[s][2] = 0;                 al[s][3] = 0;
    al[s][4] = (short)f2bf(r_q1); al[s][5] = (short)f2bf(r_x1);
    al[s][6] = 0;                 al[s][7] = 0;
  }

  f32x4 acc[4];
#pragma unroll
  for (int i = 0; i < 4; i++) acc[i] = (f32x4){0.f, 0.f, 0.f, 0.f};

#pragma unroll
  for (int s = 0; s < SPK; s++) {
    int ks = kc * SPK + s;
    const short8* bh = Bh + ((size_t)(ks * 8) + n0) * 64 + l;
    const short8* bl = Bl + ((size_t)(ks * 8) + n0) * 64 + l;
    short8 b_h0 = bh[0], b_h1 = bh[64], b_h2 = bh[128], b_h3 = bh[192];
    short8 b_l0 = bl[0], b_l1 = bl[64], b_l2 = bl[128], b_l3 = bl[192];

    acc[0] = __builtin_amdgcn_mfma_f32_16x16x32_bf16(ah[s], b_h0, acc[0], 0, 0, 0);
    acc[0] = __builtin_amdgcn_mfma_f32_16x16x32_bf16(ah[s], b_l0, acc[0], 0, 0, 0);
    acc[0] = __builtin_amdgcn_mfma_f32_16x16x32_bf16(al[s], b_h0, acc[0], 0, 0, 0);
    acc[1] = __builtin_amdgcn_mfma_f32_16x16x32_bf16(ah[s], b_h1, acc[1], 0, 0, 0);
    acc[1] = __builtin_amdgcn_mfma_f32_16x16x32_bf16(ah[s], b_l1, acc[1], 0, 0, 0);
    acc[1] = __builtin_amdgcn_mfma_f32_16x16x32_bf16(al[s], b_h1, acc[1], 0, 0, 0);
    acc[2] = __builtin_amdgcn_mfma_f32_16x16x32_bf16(ah[s], b_h2, acc[2], 0, 0, 0);
    acc[2] = __builtin_amdgcn_mfma_f32_16x16x32_bf16(ah[s], b_l2, acc[2], 0, 0, 0);
    acc[2] = __builtin_amdgcn_mfma_f32_16x16x32_bf16(al[s], b_h2, acc[2], 0, 0, 0);
    acc[3] = __builtin_amdgcn_mfma_f32_16x16x32_bf16(ah[s], b_h3, acc[3], 0, 0, 0);
    acc[3] = __builtin_amdgcn_mfma_f32_16x16x32_bf16(ah[s], b_l3, acc[3], 0, 0, 0);
    acc[3] = __builtin_amdgcn_mfma_f32_16x16x32_bf16(al[s], b_h3, acc[3], 0, 0, 0);
  }

#pragma unroll
  for (int ntl = 0; ntl < 4; ntl++)
#pragma unroll
    for (int r = 0; r < 4; r++) {
      int grow = r0 + ((l >> 4) << 2) + r;
      part[((size_t)kc * NB + grow) * NK + (n0 + ntl) * 16 + (l & 15)] = acc[ntl][r];
    }
}

// 2 rows per wave, float4 per lane (k-quad). Reduce KSPLIT partials, +log w,
// NaN fix, LSE with the reference's per-term +1e-8 (4e-8 per lane), exp.
__global__ __launch_bounds__(256) void k_final(
    const float* __restrict__ ws, float* __restrict__ out) {
  const float4* lw4   = (const float4*)(ws + OFF_LW);
  const float4* part4 = (const float4*)(ws + OFF_PART);
  int lane = threadIdx.x & 63;
  int wv   = threadIdx.x >> 6;
  int half = lane >> 5;
  int lk   = lane & 31;
  int b = blockIdx.x * 8 + wv * 2 + half;

  float4 s = make_float4(0.f, 0.f, 0.f, 0.f);
#pragma unroll
  for (int sp = 0; sp < KSPLIT; sp++) {
    float4 v = part4[((size_t)sp * NB + b) * 32 + lk];
    s.x += v.x; s.y += v.y; s.z += v.z; s.w += v.w;
  }
  float4 lv = lw4[lk];
  s.x += lv.x; s.y += lv.y; s.z += lv.z; s.w += lv.w;
  if (isnan(s.x)) s.x = 0.f;
  if (isnan(s.y)) s.y = 0.f;
  if (isnan(s.z)) s.z = 0.f;
  if (isnan(s.w)) s.w = 0.f;

  float mx = fmaxf(fmaxf(s.x, s.y), fmaxf(s.z, s.w));
#pragma unroll
  for (int off = 16; off; off >>= 1) mx = fmaxf(mx, __shfl_xor(mx, off));
  float sum = expf(s.x - mx) + expf(s.y - mx) + expf(s.z - mx) + expf(s.w - mx) + 4e-8f;
#pragma unroll
  for (int off = 16; off; off >>= 1) sum += __shfl_xor(sum, off);
  float lse = logf(sum) + mx;
  float4 o = make_float4(expf(s.x - lse), expf(s.y - lse),
                         expf(s.z - lse), expf(s.w - lse));
  ((float4*)out)[(size_t)b * 32 + lk] = o;
}

extern "C" void kernel_launch(void* const* d_in, const int* in_sizes, int n_in,
                              void* d_out, int out_size, void* d_ws, size_t ws_size,
                              hipStream_t stream) {
  const float* data = (const float*)d_in[0];
  const float* mask = (const float*)d_in[1];
  const float* wts  = (const float*)d_in[2];
  const float* mu   = (const float*)d_in[3];
  const float* cov  = (const float*)d_in[4];
  float* ws  = (float*)d_ws;
  float* out = (float*)d_out;

  k_prep<<<196, 256, 0, stream>>>(wts, mu, cov, ws);
  k_mm<<<32 * NHALF * KSPLIT, 256, 0, stream>>>(data, mask, ws);
  k_final<<<NB / 8, 256, 0, stream>>>(ws, out);
}